// Round 1
// baseline (190.443 us; speedup 1.0000x reference)
//
#include <hip/hip_runtime.h>
#include <cstdint>

#define BB 8
#define NN 2048
#define FIN 256
#define FOUT 256
#define LOG2E 1.4426950408889634f

typedef __attribute__((ext_vector_type(8))) short bf16x8;
typedef __attribute__((ext_vector_type(4))) float f32x4;

__device__ __forceinline__ unsigned short f2bf(float x){
  union { float f; unsigned u; } v; v.f = x;
  unsigned r = v.u + 0x7FFFu + ((v.u >> 16) & 1u);
  return (unsigned short)(r >> 16);
}
__device__ __forceinline__ unsigned pack2(float a, float b){
  return (unsigned)f2bf(a) | ((unsigned)f2bf(b) << 16);
}

// ---------------- K0a: h (fp32) -> bf16 ----------------
__global__ __launch_bounds__(256) void k_convert_h(const float* __restrict__ h,
                                                   unsigned short* __restrict__ hb){
  int g = blockIdx.x * 256 + threadIdx.x;          // 1,048,576 threads, 4 elems each
  float4 v = ((const float4*)h)[g];
  ushort4 o;
  o.x = f2bf(v.x); o.y = f2bf(v.y); o.z = f2bf(v.z); o.w = f2bf(v.w);
  ((ushort4*)hb)[g] = o;
}

// ---------------- K0b: W^T (bf16), o-major rows of length FIN ----------------
__global__ __launch_bounds__(256) void k_wt(const float* __restrict__ W,
                                            unsigned short* __restrict__ Wt){
  int g = blockIdx.x * 256 + threadIdx.x;          // 65536
  int o = g >> 8, k = g & 255;
  Wt[g] = f2bf(W[k * 256 + o]);
}

// ---------------- K0c: pack adjacency into bitmask (32 u64 words per row) ----------------
__global__ __launch_bounds__(256) void k_adjbits(const float* __restrict__ adj,
                                                 unsigned long long* __restrict__ ab){
  int i = blockIdx.x, tid = threadIdx.x;
  int w = tid >> 6, lane = tid & 63;
  #pragma unroll
  for (int seg = 0; seg < 8; seg++){
    int j = seg * 256 + tid;
    unsigned long long m = __ballot(adj[(size_t)i * NN + j] != 0.0f);
    if (lane == 0) ab[i * 32 + seg * 4 + w] = m;
  }
}

// ---------------- K1: Wh = h @ W  (bf16 MFMA, fp32 out) ----------------
// grid (FOUT/128=2, 16384/128=128), 256 threads, 128x128 tile, BK=64
__global__ __launch_bounds__(256, 2) void k_gemm_wh(const unsigned short* __restrict__ hb,
                                                    const unsigned short* __restrict__ Wt,
                                                    float* __restrict__ Wh){
  __shared__ unsigned short As[128 * 72];
  __shared__ unsigned short Bs[128 * 72];
  const int tid = threadIdx.x;
  const int r0 = blockIdx.y * 128, o0 = blockIdx.x * 128;
  const int w = tid >> 6, lane = tid & 63, lhi = lane >> 4, llo = lane & 15;
  const int wr = (w >> 1) * 64, wc = (w & 1) * 64;
  f32x4 acc[4][4];
  #pragma unroll
  for (int i = 0; i < 4; i++)
    #pragma unroll
    for (int j = 0; j < 4; j++){ acc[i][j][0]=0.f; acc[i][j][1]=0.f; acc[i][j][2]=0.f; acc[i][j][3]=0.f; }

  const int lr = tid >> 1;          // staging row 0..127
  const int lc = (tid & 1) * 32;    // element offset 0/32

  for (int k0 = 0; k0 < 256; k0 += 64){
    const unsigned short* ap = hb + (size_t)(r0 + lr) * 256 + k0 + lc;
    const unsigned short* bp = Wt + (size_t)(o0 + lr) * 256 + k0 + lc;
    uint4 a0 = *(const uint4*)(ap);      uint4 a1 = *(const uint4*)(ap + 8);
    uint4 a2 = *(const uint4*)(ap + 16); uint4 a3 = *(const uint4*)(ap + 24);
    uint4 b0 = *(const uint4*)(bp);      uint4 b1 = *(const uint4*)(bp + 8);
    uint4 b2 = *(const uint4*)(bp + 16); uint4 b3 = *(const uint4*)(bp + 24);
    *(uint4*)&As[lr * 72 + lc]      = a0; *(uint4*)&As[lr * 72 + lc + 8]  = a1;
    *(uint4*)&As[lr * 72 + lc + 16] = a2; *(uint4*)&As[lr * 72 + lc + 24] = a3;
    *(uint4*)&Bs[lr * 72 + lc]      = b0; *(uint4*)&Bs[lr * 72 + lc + 8]  = b1;
    *(uint4*)&Bs[lr * 72 + lc + 16] = b2; *(uint4*)&Bs[lr * 72 + lc + 24] = b3;
    __syncthreads();
    #pragma unroll
    for (int kk = 0; kk < 2; kk++){
      bf16x8 af[4], bf[4];
      #pragma unroll
      for (int t = 0; t < 4; t++)
        af[t] = *(const bf16x8*)&As[(wr + t * 16 + llo) * 72 + kk * 32 + lhi * 8];
      #pragma unroll
      for (int t = 0; t < 4; t++)
        bf[t] = *(const bf16x8*)&Bs[(wc + t * 16 + llo) * 72 + kk * 32 + lhi * 8];
      #pragma unroll
      for (int it = 0; it < 4; it++)
        #pragma unroll
        for (int ot = 0; ot < 4; ot++)
          acc[it][ot] = __builtin_amdgcn_mfma_f32_16x16x32_bf16(af[it], bf[ot], acc[it][ot], 0, 0, 0);
    }
    __syncthreads();
  }
  #pragma unroll
  for (int it = 0; it < 4; it++){
    int row = r0 + wr + it * 16 + lhi * 4;
    #pragma unroll
    for (int ot = 0; ot < 4; ot++){
      int col = o0 + wc + ot * 16 + llo;
      float* op = Wh + (size_t)row * 256 + col;
      #pragma unroll
      for (int q = 0; q < 4; q++) op[(size_t)q * 256] = acc[it][ot][q];
    }
  }
}

// ---------------- K2: s1c,s2c = (Wh·a1, Wh·a2) * log2e ----------------
__global__ __launch_bounds__(256) void k_s12(const float* __restrict__ Wh,
                                             const float* __restrict__ a,
                                             float* __restrict__ s1c, float* __restrict__ s2c){
  int r = blockIdx.x * 4 + (threadIdx.x >> 6);
  int lane = threadIdx.x & 63;
  float4 wv = *(const float4*)(Wh + (size_t)r * 256 + lane * 4);
  float4 a1 = *(const float4*)(a + lane * 4);
  float4 a2 = *(const float4*)(a + 256 + lane * 4);
  float d1 = wv.x * a1.x + wv.y * a1.y + wv.z * a1.z + wv.w * a1.w;
  float d2 = wv.x * a2.x + wv.y * a2.y + wv.z * a2.z + wv.w * a2.w;
  #pragma unroll
  for (int o = 32; o; o >>= 1){ d1 += __shfl_xor(d1, o); d2 += __shfl_xor(d2, o); }
  if (lane == 0){ s1c[r] = d1 * LOG2E; s2c[r] = d2 * LOG2E; }
}

// ---------------- K2b: WhT (bf16) = transpose(Wh) per batch ----------------
// grid (N/32=64, FOUT/32=8, B=8)
__global__ __launch_bounds__(256) void k_wht(const float* __restrict__ Wh,
                                             unsigned short* __restrict__ WhT){
  __shared__ float t[32][33];
  int n0 = blockIdx.x * 32, o0 = blockIdx.y * 32, b = blockIdx.z;
  int r = threadIdx.x >> 3, c4 = (threadIdx.x & 7) * 4;
  float4 v = *(const float4*)(Wh + (size_t)(b * NN + n0 + r) * 256 + o0 + c4);
  t[r][c4] = v.x; t[r][c4 + 1] = v.y; t[r][c4 + 2] = v.z; t[r][c4 + 3] = v.w;
  __syncthreads();
  ushort4 u;
  u.x = f2bf(t[c4 + 0][r]); u.y = f2bf(t[c4 + 1][r]);
  u.z = f2bf(t[c4 + 2][r]); u.w = f2bf(t[c4 + 3][r]);
  *(ushort4*)(WhT + (size_t)(b * 256 + o0 + r) * 2048 + n0 + c4) = u;
}

// ---------------- K3: row stats mc (scaled max), linv = 1/sum ----------------
// grid (N, B), 256 threads per row
__global__ __launch_bounds__(256) void k_stats(const float* __restrict__ s1c,
                                               const float* __restrict__ s2c,
                                               const unsigned long long* __restrict__ ab,
                                               float* __restrict__ mc, float* __restrict__ linv){
  const int i = blockIdx.x, b = blockIdx.y, tid = threadIdx.x;
  const int w = tid >> 6, lane = tid & 63;
  const float s1 = s1c[b * NN + i];
  const unsigned long long* wrow = ab + (size_t)i * 32;
  float vals[8];
  float vmax = -3.0e38f;
  #pragma unroll
  for (int t = 0; t < 8; t++){
    int j = t * 256 + tid;
    float x = s1 + s2c[b * NN + j];
    x = fmaxf(x, 0.2f * x);
    bool on = (wrow[j >> 6] >> (j & 63)) & 1ull;
    x = on ? x : -3.0e38f;
    vals[t] = x;
    vmax = fmaxf(vmax, x);
  }
  #pragma unroll
  for (int o = 32; o; o >>= 1) vmax = fmaxf(vmax, __shfl_xor(vmax, o));
  __shared__ float redm[4], reds[4];
  if (lane == 0) redm[w] = vmax;
  __syncthreads();
  float m = fmaxf(fmaxf(redm[0], redm[1]), fmaxf(redm[2], redm[3]));
  float s = 0.f;
  #pragma unroll
  for (int t = 0; t < 8; t++) s += __builtin_amdgcn_exp2f(vals[t] - m);
  #pragma unroll
  for (int o = 32; o; o >>= 1) s += __shfl_xor(s, o);
  if (lane == 0) reds[w] = s;
  __syncthreads();
  if (tid == 0){
    float l = reds[0] + reds[1] + reds[2] + reds[3];
    mc[b * NN + i] = m;
    linv[b * NN + i] = 1.0f / l;
  }
}

// ---------------- K4: h' = softmax(P) @ Wh  (fused, flash-style) ----------------
// grid (FOUT/64=4, N/128=16, B=8), 256 threads; BM=128, BN=64, BK=64
__global__ __launch_bounds__(256, 2) void k_attn(const float* __restrict__ s1c,
                                                 const float* __restrict__ s2c,
                                                 const float* __restrict__ mc,
                                                 const float* __restrict__ linv,
                                                 const unsigned short* __restrict__ WhT,
                                                 const unsigned long long* __restrict__ ab,
                                                 float* __restrict__ out){
  __shared__ float s2s[2048];
  __shared__ float s1s[128], msd[128], ls[128];
  __shared__ unsigned short Ps[128 * 72];
  __shared__ unsigned short Ws[64 * 72];
  const int tid = threadIdx.x;
  const int b = blockIdx.z, i0 = blockIdx.y * 128, o0 = blockIdx.x * 64;
  for (int t = tid; t < 2048; t += 256) s2s[t] = s2c[b * NN + t];
  if (tid < 128){
    s1s[tid] = s1c[b * NN + i0 + tid];
    msd[tid] = mc[b * NN + i0 + tid];
    ls[tid]  = linv[b * NN + i0 + tid];
  }
  __syncthreads();
  const int w = tid >> 6, lane = tid & 63, lhi = lane >> 4, llo = lane & 15;
  f32x4 acc[2][4];
  #pragma unroll
  for (int i = 0; i < 2; i++)
    #pragma unroll
    for (int j = 0; j < 4; j++){ acc[i][j][0]=0.f; acc[i][j][1]=0.f; acc[i][j][2]=0.f; acc[i][j][3]=0.f; }

  const int pi = tid >> 1;          // P row 0..127
  const int pj = (tid & 1) * 32;    // j offset within BK
  const int wrow = tid >> 2;        // Ws row 0..63
  const int wcol = (tid & 3) * 16;  // element offset
  const float s1v = s1s[pi], mv = msd[pi];
  const unsigned long long* abrow = ab + (size_t)(i0 + pi) * 32;

  for (int j0 = 0; j0 < NN; j0 += 64){
    const unsigned short* wp = WhT + (size_t)(b * 256 + o0 + wrow) * 2048 + j0 + wcol;
    uint4 wv0 = *(const uint4*)wp;
    uint4 wv1 = *(const uint4*)(wp + 8);

    unsigned bits = (unsigned)(abrow[j0 >> 6] >> pj);
    #pragma unroll
    for (int g = 0; g < 4; g++){
      float p[8];
      #pragma unroll
      for (int e = 0; e < 8; e++){
        int jj = g * 8 + e;
        float x = s1v + s2s[j0 + pj + jj];
        float y = fmaxf(x, 0.2f * x) - mv;
        p[e] = ((bits >> jj) & 1u) ? __builtin_amdgcn_exp2f(y) : 0.0f;
      }
      uint4 q = make_uint4(pack2(p[0], p[1]), pack2(p[2], p[3]),
                           pack2(p[4], p[5]), pack2(p[6], p[7]));
      *(uint4*)&Ps[pi * 72 + pj + g * 8] = q;
    }
    *(uint4*)&Ws[wrow * 72 + wcol]     = wv0;
    *(uint4*)&Ws[wrow * 72 + wcol + 8] = wv1;
    __syncthreads();
    #pragma unroll
    for (int kk = 0; kk < 2; kk++){
      bf16x8 a0 = *(const bf16x8*)&Ps[(w * 32 + llo) * 72 + kk * 32 + lhi * 8];
      bf16x8 a1 = *(const bf16x8*)&Ps[(w * 32 + 16 + llo) * 72 + kk * 32 + lhi * 8];
      bf16x8 bfr[4];
      #pragma unroll
      for (int ot = 0; ot < 4; ot++)
        bfr[ot] = *(const bf16x8*)&Ws[(ot * 16 + llo) * 72 + kk * 32 + lhi * 8];
      #pragma unroll
      for (int ot = 0; ot < 4; ot++){
        acc[0][ot] = __builtin_amdgcn_mfma_f32_16x16x32_bf16(a0, bfr[ot], acc[0][ot], 0, 0, 0);
        acc[1][ot] = __builtin_amdgcn_mfma_f32_16x16x32_bf16(a1, bfr[ot], acc[1][ot], 0, 0, 0);
      }
    }
    __syncthreads();
  }
  #pragma unroll
  for (int it = 0; it < 2; it++){
    int rloc = w * 32 + it * 16 + lhi * 4;
    #pragma unroll
    for (int ot = 0; ot < 4; ot++){
      int col = o0 + ot * 16 + llo;
      #pragma unroll
      for (int q = 0; q < 4; q++){
        float v = acc[it][ot][q] * ls[rloc + q];
        out[(size_t)(b * NN + i0 + rloc + q) * 256 + col] = v;
      }
    }
  }
}

extern "C" void kernel_launch(void* const* d_in, const int* in_sizes, int n_in,
                              void* d_out, int out_size, void* d_ws, size_t ws_size,
                              hipStream_t stream) {
  const float* h   = (const float*)d_in[0];
  const float* adj = (const float*)d_in[1];
  const float* W   = (const float*)d_in[2];
  const float* a   = (const float*)d_in[3];
  float* out = (float*)d_out;

  char* ws = (char*)d_ws;
  unsigned short* hb       = (unsigned short*)(ws);                 //  8,388,608 B
  unsigned short* WhT      = (unsigned short*)(ws + 8388608);       //  8,388,608 B
  float* Wh                = (float*)(ws + 16777216);               // 16,777,216 B
  unsigned short* Wt       = (unsigned short*)(ws + 33554432);      //    131,072 B
  unsigned long long* ab   = (unsigned long long*)(ws + 33685504);  //    524,288 B
  float* s1c               = (float*)(ws + 34209792);               //     65,536 B
  float* s2c               = (float*)(ws + 34275328);               //     65,536 B
  float* mcp               = (float*)(ws + 34340864);               //     65,536 B
  float* lin               = (float*)(ws + 34406400);               //     65,536 B

  hipLaunchKernelGGL(k_convert_h, dim3(4096), dim3(256), 0, stream, h, hb);
  hipLaunchKernelGGL(k_wt,        dim3(256),  dim3(256), 0, stream, W, Wt);
  hipLaunchKernelGGL(k_adjbits,   dim3(2048), dim3(256), 0, stream, adj, ab);
  hipLaunchKernelGGL(k_gemm_wh,   dim3(2, 128), dim3(256), 0, stream, hb, Wt, Wh);
  hipLaunchKernelGGL(k_s12,       dim3(4096), dim3(256), 0, stream, Wh, a, s1c, s2c);
  hipLaunchKernelGGL(k_wht,       dim3(64, 8, 8), dim3(256), 0, stream, Wh, WhT);
  hipLaunchKernelGGL(k_stats,     dim3(2048, 8), dim3(256), 0, stream, s1c, s2c, ab, mcp, lin);
  hipLaunchKernelGGL(k_attn,      dim3(4, 16, 8), dim3(256), 0, stream, s1c, s2c, mcp, lin, WhT, ab, out);
}

// Round 2
// 143.283 us; speedup vs baseline: 1.3291x; 1.3291x over previous
//
#include <hip/hip_runtime.h>
#include <cstdint>

#define BB 8
#define NN 2048
#define FF 256
#define LOG2E 1.4426950408889634f

typedef __attribute__((ext_vector_type(8))) short bf16x8;
typedef __attribute__((ext_vector_type(4))) float f32x4;

__device__ __forceinline__ unsigned short f2bf(float x){
  union { float f; unsigned u; } v; v.f = x;
  unsigned r = v.u + 0x7FFFu + ((v.u >> 16) & 1u);
  return (unsigned short)(r >> 16);
}
__device__ __forceinline__ unsigned pack2(float a, float b){
  return (unsigned)f2bf(a) | ((unsigned)f2bf(b) << 16);
}

// ---------------- K0b: W^T (bf16), o-major rows of length FIN ----------------
__global__ __launch_bounds__(256) void k_wt(const float* __restrict__ W,
                                            unsigned short* __restrict__ Wt){
  int g = blockIdx.x * 256 + threadIdx.x;          // 65536
  int o = g >> 8, k = g & 255;
  Wt[g] = f2bf(W[k * 256 + o]);
}

// ---------------- K0c: pack adjacency into bitmask (32 u64 words per row) ----------------
__global__ __launch_bounds__(256) void k_adjbits(const float* __restrict__ adj,
                                                 unsigned long long* __restrict__ ab){
  int i = blockIdx.x, tid = threadIdx.x;
  int w = tid >> 6, lane = tid & 63;
  #pragma unroll
  for (int seg = 0; seg < 8; seg++){
    int j = seg * 256 + tid;
    unsigned long long m = __ballot(adj[(size_t)i * NN + j] != 0.0f);
    if (lane == 0) ab[i * 32 + seg * 4 + w] = m;
  }
}

// ---------------- K1: fused  Wh=h@W (bf16 MFMA) -> s1,s2 (scaled by log2e) + WhT(bf16) ----------------
// grid 256 (one block per 64 global rows), 256 threads; BM=64, BO=256, BK=64
__global__ __launch_bounds__(256) void k_fused_gemm(const float* __restrict__ h,
                                                    const unsigned short* __restrict__ Wt,
                                                    const float* __restrict__ a,
                                                    unsigned short* __restrict__ WhT,
                                                    float* __restrict__ s1c,
                                                    float* __restrict__ s2c){
  __shared__ unsigned short As[64 * 72];     //  9216 B
  __shared__ unsigned short Bs[256 * 72];    // 36864 B (reused as transpose buffer)
  __shared__ float s1p[4][64], s2p[4][64];   //  2048 B
  const int tid = threadIdx.x;
  const int r0 = blockIdx.x * 64;            // global row (over B*N)
  const int b  = r0 >> 11;
  const int i0 = r0 & (NN - 1);
  const int w = tid >> 6, lane = tid & 63, lhi = lane >> 4, llo = lane & 15;
  const int wc = w * 64;

  f32x4 acc[4][4];
  #pragma unroll
  for (int i = 0; i < 4; i++)
    #pragma unroll
    for (int j = 0; j < 4; j++){ acc[i][j][0]=0.f; acc[i][j][1]=0.f; acc[i][j][2]=0.f; acc[i][j][3]=0.f; }

  const int ar = tid >> 2;            // A staging row 0..63
  const int as = (tid & 3) * 16;      // 16-elem segment

  for (int k0 = 0; k0 < 256; k0 += 64){
    // ---- A: read h fp32, convert to bf16 in LDS ----
    const float* hp = h + (size_t)(r0 + ar) * 256 + k0 + as;
    float4 v0 = *(const float4*)(hp);      float4 v1 = *(const float4*)(hp + 4);
    float4 v2 = *(const float4*)(hp + 8);  float4 v3 = *(const float4*)(hp + 12);
    uint4 q0 = make_uint4(pack2(v0.x, v0.y), pack2(v0.z, v0.w),
                          pack2(v1.x, v1.y), pack2(v1.z, v1.w));
    uint4 q1 = make_uint4(pack2(v2.x, v2.y), pack2(v2.z, v2.w),
                          pack2(v3.x, v3.y), pack2(v3.z, v3.w));
    *(uint4*)&As[ar * 72 + as]     = q0;
    *(uint4*)&As[ar * 72 + as + 8] = q1;
    // ---- B: Wt tile 256 x 64 ----
    #pragma unroll
    for (int p = 0; p < 8; p++){
      int o = p * 32 + (tid >> 3), col = (tid & 7) * 8;
      *(uint4*)&Bs[o * 72 + col] = *(const uint4*)(Wt + (size_t)o * 256 + k0 + col);
    }
    __syncthreads();
    #pragma unroll
    for (int kk = 0; kk < 2; kk++){
      bf16x8 af[4], bfr[4];
      #pragma unroll
      for (int t = 0; t < 4; t++)
        af[t] = *(const bf16x8*)&As[(t * 16 + llo) * 72 + kk * 32 + lhi * 8];
      #pragma unroll
      for (int t = 0; t < 4; t++)
        bfr[t] = *(const bf16x8*)&Bs[(wc + t * 16 + llo) * 72 + kk * 32 + lhi * 8];
      #pragma unroll
      for (int it = 0; it < 4; it++)
        #pragma unroll
        for (int ot = 0; ot < 4; ot++)
          acc[it][ot] = __builtin_amdgcn_mfma_f32_16x16x32_bf16(af[it], bfr[ot], acc[it][ot], 0, 0, 0);
    }
    __syncthreads();
  }

  // ---- epilogue 1: s1/s2 partial dots (log2e folded into a) ----
  float a1v[4], a2v[4];
  #pragma unroll
  for (int ot = 0; ot < 4; ot++){
    a1v[ot] = a[wc + ot * 16 + llo] * LOG2E;
    a2v[ot] = a[256 + wc + ot * 16 + llo] * LOG2E;
  }
  #pragma unroll
  for (int it = 0; it < 4; it++){
    #pragma unroll
    for (int q = 0; q < 4; q++){
      float p1 = 0.f, p2 = 0.f;
      #pragma unroll
      for (int ot = 0; ot < 4; ot++){
        p1 += acc[it][ot][q] * a1v[ot];
        p2 += acc[it][ot][q] * a2v[ot];
      }
      #pragma unroll
      for (int o = 1; o < 16; o <<= 1){ p1 += __shfl_xor(p1, o); p2 += __shfl_xor(p2, o); }
      if (llo == 0){
        s1p[w][it * 16 + lhi * 4 + q] = p1;
        s2p[w][it * 16 + lhi * 4 + q] = p2;
      }
    }
  }

  // ---- epilogue 2: transpose acc (bf16) into Bs = WhT tile (256 o-rows x 64 i-cols) ----
  #pragma unroll
  for (int it = 0; it < 4; it++){
    #pragma unroll
    for (int ot = 0; ot < 4; ot++){
      int o = wc + ot * 16 + llo;
      uint2 u = make_uint2(pack2(acc[it][ot][0], acc[it][ot][1]),
                           pack2(acc[it][ot][2], acc[it][ot][3]));
      *(uint2*)&Bs[o * 72 + it * 16 + lhi * 4] = u;
    }
  }
  __syncthreads();

  if (tid < 64){
    s1c[r0 + tid] = s1p[0][tid] + s1p[1][tid] + s1p[2][tid] + s1p[3][tid];
    s2c[r0 + tid] = s2p[0][tid] + s2p[1][tid] + s2p[2][tid] + s2p[3][tid];
  }
  #pragma unroll
  for (int p = 0; p < 8; p++){
    int o = p * 32 + (tid >> 3), col = (tid & 7) * 8;
    *(uint4*)(WhT + (size_t)(b * 256 + o) * 2048 + i0 + col) = *(const uint4*)&Bs[o * 72 + col];
  }
}

// ---------------- K4: h' = softmax(P) @ Wh  (fused, one pass, bound-max) ----------------
// grid (N/64=32, B=8), 256 threads; BM=64, BO=256, BK=64
__global__ __launch_bounds__(256) void k_attn(const float* __restrict__ s1c,
                                              const float* __restrict__ s2c,
                                              const unsigned short* __restrict__ WhT,
                                              const unsigned long long* __restrict__ ab,
                                              float* __restrict__ out){
  __shared__ float s2s[2048];                //  8192 B
  __shared__ unsigned short Ps[64 * 72];     //  9216 B
  __shared__ unsigned short Ws[256 * 72];    // 36864 B
  __shared__ float s1s[64], lin[64], red[4];
  const int tid = threadIdx.x;
  const int b = blockIdx.y, i0 = blockIdx.x * 64;
  const int w = tid >> 6, lane = tid & 63, lhi = lane >> 4, llo = lane & 15;
  const int wc = w * 64;

  // stage s2 (full row space) + block max; stage s1 tile
  float vmax = -3.0e38f;
  #pragma unroll
  for (int k = 0; k < 2; k++){
    int idx = k * 256 + tid;                 // float4 index, 512 total
    float4 v = ((const float4*)(s2c + (size_t)b * NN))[idx];
    ((float4*)s2s)[idx] = v;
    vmax = fmaxf(vmax, fmaxf(fmaxf(v.x, v.y), fmaxf(v.z, v.w)));
  }
  #pragma unroll
  for (int o = 32; o; o >>= 1) vmax = fmaxf(vmax, __shfl_xor(vmax, o));
  if (lane == 0) red[w] = vmax;
  if (tid < 64) s1s[tid] = s1c[(size_t)b * NN + i0 + tid];
  __syncthreads();
  const float m2 = fmaxf(fmaxf(red[0], red[1]), fmaxf(red[2], red[3]));

  const int pi = tid >> 2;                   // P row 0..63
  const int pj = (tid & 3) * 16;             // 16 j's per thread
  const float s1v = s1s[pi];
  const float xm = s1v + m2;
  const float mv = fmaxf(xm, 0.2f * xm);     // upper bound of row max (lrelu monotone)
  const unsigned long long* abrow = ab + (size_t)(i0 + pi) * 32;
  float rs = 0.f;

  f32x4 acc[4][4];
  #pragma unroll
  for (int i = 0; i < 4; i++)
    #pragma unroll
    for (int j = 0; j < 4; j++){ acc[i][j][0]=0.f; acc[i][j][1]=0.f; acc[i][j][2]=0.f; acc[i][j][3]=0.f; }

  for (int j0 = 0; j0 < NN; j0 += 64){
    // ---- stage Ws: WhT tile 256 x 64 ----
    #pragma unroll
    for (int p = 0; p < 8; p++){
      int o = p * 32 + (tid >> 3), col = (tid & 7) * 8;
      *(uint4*)&Ws[o * 72 + col] = *(const uint4*)(WhT + (size_t)(b * 256 + o) * 2048 + j0 + col);
    }
    // ---- compute P tile 64 x 64 (each element once) ----
    unsigned bits = (unsigned)((abrow[j0 >> 6] >> pj) & 0xFFFFull);
    float pv[16];
    #pragma unroll
    for (int e = 0; e < 16; e++){
      float x = s1v + s2s[j0 + pj + e];
      float y = fmaxf(x, 0.2f * x) - mv;
      pv[e] = ((bits >> e) & 1u) ? __builtin_amdgcn_exp2f(y) : 0.0f;
      rs += pv[e];
    }
    uint4 q0 = make_uint4(pack2(pv[0], pv[1]),  pack2(pv[2], pv[3]),
                          pack2(pv[4], pv[5]),  pack2(pv[6], pv[7]));
    uint4 q1 = make_uint4(pack2(pv[8], pv[9]),  pack2(pv[10], pv[11]),
                          pack2(pv[12], pv[13]), pack2(pv[14], pv[15]));
    *(uint4*)&Ps[pi * 72 + pj]     = q0;
    *(uint4*)&Ps[pi * 72 + pj + 8] = q1;
    __syncthreads();
    #pragma unroll
    for (int kk = 0; kk < 2; kk++){
      bf16x8 af[4], bfr[4];
      #pragma unroll
      for (int t = 0; t < 4; t++)
        af[t] = *(const bf16x8*)&Ps[(t * 16 + llo) * 72 + kk * 32 + lhi * 8];
      #pragma unroll
      for (int t = 0; t < 4; t++)
        bfr[t] = *(const bf16x8*)&Ws[(wc + t * 16 + llo) * 72 + kk * 32 + lhi * 8];
      #pragma unroll
      for (int it = 0; it < 4; it++)
        #pragma unroll
        for (int ot = 0; ot < 4; ot++)
          acc[it][ot] = __builtin_amdgcn_mfma_f32_16x16x32_bf16(af[it], bfr[ot], acc[it][ot], 0, 0, 0);
    }
    __syncthreads();
  }

  // ---- row sums -> 1/l ----
  rs += __shfl_xor(rs, 1);
  rs += __shfl_xor(rs, 2);
  if ((tid & 3) == 0) lin[pi] = 1.0f / rs;
  __syncthreads();

  // ---- epilogue: scale + store ----
  #pragma unroll
  for (int it = 0; it < 4; it++){
    #pragma unroll
    for (int ot = 0; ot < 4; ot++){
      int col = wc + ot * 16 + llo;
      #pragma unroll
      for (int q = 0; q < 4; q++){
        int row = it * 16 + lhi * 4 + q;
        out[(size_t)(b * NN + i0 + row) * 256 + col] = acc[it][ot][q] * lin[row];
      }
    }
  }
}

extern "C" void kernel_launch(void* const* d_in, const int* in_sizes, int n_in,
                              void* d_out, int out_size, void* d_ws, size_t ws_size,
                              hipStream_t stream) {
  const float* h   = (const float*)d_in[0];
  const float* adj = (const float*)d_in[1];
  const float* W   = (const float*)d_in[2];
  const float* a   = (const float*)d_in[3];
  float* out = (float*)d_out;

  char* ws = (char*)d_ws;
  unsigned short* WhT      = (unsigned short*)(ws);                 // 8,388,608 B
  unsigned short* Wt       = (unsigned short*)(ws + 8388608);       //   131,072 B
  unsigned long long* ab   = (unsigned long long*)(ws + 8519680);   //   524,288 B
  float* s1c               = (float*)(ws + 9043968);                //    65,536 B
  float* s2c               = (float*)(ws + 9109504);                //    65,536 B

  hipLaunchKernelGGL(k_wt,         dim3(256),    dim3(256), 0, stream, W, Wt);
  hipLaunchKernelGGL(k_adjbits,    dim3(2048),   dim3(256), 0, stream, adj, ab);
  hipLaunchKernelGGL(k_fused_gemm, dim3(256),    dim3(256), 0, stream, h, Wt, a, WhT, s1c, s2c);
  hipLaunchKernelGGL(k_attn,       dim3(32, 8),  dim3(256), 0, stream, s1c, s2c, WhT, ab, out);
}

// Round 3
// 139.100 us; speedup vs baseline: 1.3691x; 1.0301x over previous
//
#include <hip/hip_runtime.h>
#include <cstdint>

#define NN 2048
#define LOG2E 1.4426950408889634f

typedef __attribute__((ext_vector_type(8))) short bf16x8;
typedef __attribute__((ext_vector_type(4))) float f32x4;

__device__ __forceinline__ unsigned short f2bf(float x){
  union { float f; unsigned u; } v; v.f = x;
  unsigned r = v.u + 0x7FFFu + ((v.u >> 16) & 1u);
  return (unsigned short)(r >> 16);
}
__device__ __forceinline__ unsigned pack2(float a, float b){
  return (unsigned)f2bf(a) | ((unsigned)f2bf(b) << 16);
}
// pack two already-truncated uints (value & 0xFFFF0000): (lo>>16)|(hi&0xFFFF0000) in 1 inst
__device__ __forceinline__ unsigned permpack(unsigned hi, unsigned lo){
  return __builtin_amdgcn_perm(hi, lo, 0x07060302u);
}

// ---------------- K0: adj->bitmask (blocks 0..2047) + W^T bf16 (blocks 2048..2303) ----------------
__global__ __launch_bounds__(256) void k_prep(const float* __restrict__ adj,
                                              const float* __restrict__ W,
                                              unsigned long long* __restrict__ ab,
                                              unsigned short* __restrict__ Wt){
  int tid = threadIdx.x;
  if (blockIdx.x < 2048){
    int i = blockIdx.x;
    int w = tid >> 6, lane = tid & 63;
    #pragma unroll
    for (int seg = 0; seg < 8; seg++){
      int j = seg * 256 + tid;
      unsigned long long m = __ballot(adj[(size_t)i * NN + j] != 0.0f);
      if (lane == 0) ab[i * 32 + seg * 4 + w] = m;
    }
  } else {
    int g = (blockIdx.x - 2048) * 256 + tid;   // g = o*256 + k
    int o = g >> 8, k = g & 255;
    Wt[g] = f2bf(W[k * 256 + o]);
  }
}

// ---------------- K1: fused Wh=h@W -> s1,s2 (log2e-scaled) + WhT(bf16) ----------------
// grid 256 (64 global rows each), 512 threads (8 waves). BM=64, BO=256, BK=64.
// Wave w owns o-columns [w*32, w*32+32): B-frags loaded DIRECTLY from global, double-buffered.
__global__ __launch_bounds__(512, 2) void k_fused_gemm(const float* __restrict__ h,
                                                       const unsigned short* __restrict__ Wt,
                                                       const float* __restrict__ a,
                                                       unsigned short* __restrict__ WhT,
                                                       float* __restrict__ s1c,
                                                       float* __restrict__ s2c){
  __shared__ __align__(16) unsigned short As[64 * 72];   //  9216 B
  __shared__ __align__(16) unsigned short Ts[256 * 72];  // 36864 B (transpose-out buffer)
  __shared__ float s1p[8][64], s2p[8][64];               //  4096 B
  const int tid = threadIdx.x;
  const int r0 = blockIdx.x * 64;
  const int b  = r0 >> 11;
  const int i0 = r0 & (NN - 1);
  const int w = tid >> 6, lane = tid & 63, lhi = lane >> 4, llo = lane & 15;
  const int wc = w * 32;

  f32x4 acc[4][2];
  #pragma unroll
  for (int i = 0; i < 4; i++)
    #pragma unroll
    for (int j = 0; j < 2; j++){ acc[i][j][0]=0.f; acc[i][j][1]=0.f; acc[i][j][2]=0.f; acc[i][j][3]=0.f; }

  const int ar = tid >> 3;            // A staging row 0..63
  const int as_ = (tid & 7) * 8;      // 8-float segment

  auto loadB = [&](int k0, bf16x8* dst){
    #pragma unroll
    for (int ot = 0; ot < 2; ot++)
      #pragma unroll
      for (int kk = 0; kk < 2; kk++)
        dst[ot * 2 + kk] = *(const bf16x8*)(Wt + (size_t)(wc + ot * 16 + llo) * 256 + k0 + kk * 32 + lhi * 8);
  };

  auto stage = [&](int k0, bf16x8* cur, bf16x8* nxt, bool ld){
    const float* hp = h + (size_t)(r0 + ar) * 256 + k0 + as_;
    float4 v0 = *(const float4*)hp;
    float4 v1 = *(const float4*)(hp + 4);
    uint4 q = make_uint4(pack2(v0.x, v0.y), pack2(v0.z, v0.w),
                         pack2(v1.x, v1.y), pack2(v1.z, v1.w));
    __syncthreads();
    *(uint4*)&As[ar * 72 + as_] = q;
    __syncthreads();
    if (ld) loadB(k0 + 64, nxt);
    #pragma unroll
    for (int kk = 0; kk < 2; kk++){
      bf16x8 af[4];
      #pragma unroll
      for (int it = 0; it < 4; it++)
        af[it] = *(const bf16x8*)&As[(it * 16 + llo) * 72 + kk * 32 + lhi * 8];
      #pragma unroll
      for (int it = 0; it < 4; it++)
        #pragma unroll
        for (int ot = 0; ot < 2; ot++)
          acc[it][ot] = __builtin_amdgcn_mfma_f32_16x16x32_bf16(af[it], cur[ot * 2 + kk], acc[it][ot], 0, 0, 0);
    }
  };

  bf16x8 b0[4], b1[4];
  loadB(0, b0);
  stage(0,   b0, b1, true);
  stage(64,  b1, b0, true);
  stage(128, b0, b1, true);
  stage(192, b1, b0, false);

  // ---- epilogue 1: s1/s2 partial dots (log2e folded) ----
  float a1v[2], a2v[2];
  #pragma unroll
  for (int ot = 0; ot < 2; ot++){
    a1v[ot] = a[wc + ot * 16 + llo] * LOG2E;
    a2v[ot] = a[256 + wc + ot * 16 + llo] * LOG2E;
  }
  #pragma unroll
  for (int it = 0; it < 4; it++){
    #pragma unroll
    for (int q = 0; q < 4; q++){
      float p1 = acc[it][0][q] * a1v[0] + acc[it][1][q] * a1v[1];
      float p2 = acc[it][0][q] * a2v[0] + acc[it][1][q] * a2v[1];
      #pragma unroll
      for (int o = 1; o < 16; o <<= 1){ p1 += __shfl_xor(p1, o); p2 += __shfl_xor(p2, o); }
      if (llo == 0){
        s1p[w][it * 16 + lhi * 4 + q] = p1;
        s2p[w][it * 16 + lhi * 4 + q] = p2;
      }
    }
  }

  // ---- epilogue 2: transpose acc (bf16, round) into Ts[o][i_local] ----
  #pragma unroll
  for (int it = 0; it < 4; it++){
    #pragma unroll
    for (int ot = 0; ot < 2; ot++){
      int o = wc + ot * 16 + llo;
      uint2 u = make_uint2(pack2(acc[it][ot][0], acc[it][ot][1]),
                           pack2(acc[it][ot][2], acc[it][ot][3]));
      *(uint2*)&Ts[o * 72 + it * 16 + lhi * 4] = u;
    }
  }
  __syncthreads();

  if (tid < 64){
    float t1 = 0.f, t2 = 0.f;
    #pragma unroll
    for (int g = 0; g < 8; g++){ t1 += s1p[g][tid]; t2 += s2p[g][tid]; }
    s1c[r0 + tid] = t1;
    s2c[r0 + tid] = t2;
  }
  #pragma unroll
  for (int p = 0; p < 4; p++){
    int o = p * 64 + (tid >> 3), col = (tid & 7) * 8;
    *(uint4*)(WhT + (size_t)(b * 256 + o) * 2048 + i0 + col) = *(const uint4*)&Ts[o * 72 + col];
  }
}

// ---------------- K2: h' = softmax(P) @ Wh (fused, bound-max, direct-B, double-buffered) ----------------
// grid (N/64=32, B=8), 512 threads (8 waves). BM=64, BO=256, BK=64.
__global__ __launch_bounds__(512, 2) void k_attn(const float* __restrict__ s1c,
                                                 const float* __restrict__ s2c,
                                                 const unsigned short* __restrict__ WhT,
                                                 const unsigned long long* __restrict__ ab,
                                                 float* __restrict__ out){
  __shared__ __align__(16) float s2s[2048];              // 8192 B
  __shared__ __align__(16) unsigned short Ps[64 * 72];   // 9216 B
  __shared__ float s1s[64], lin[64], red[8];
  const int tid = threadIdx.x;
  const int b = blockIdx.y, i0 = blockIdx.x * 64;
  const int w = tid >> 6, lane = tid & 63, lhi = lane >> 4, llo = lane & 15;
  const int wc = w * 32;

  // stage s2 (whole batch row-space) + its max; stage s1 tile
  float4 v = ((const float4*)(s2c + (size_t)b * NN))[tid];
  ((float4*)s2s)[tid] = v;
  float vmax = fmaxf(fmaxf(v.x, v.y), fmaxf(v.z, v.w));
  #pragma unroll
  for (int o = 32; o; o >>= 1) vmax = fmaxf(vmax, __shfl_xor(vmax, o));
  if (lane == 0) red[w] = vmax;
  if (tid < 64) s1s[tid] = s1c[(size_t)b * NN + i0 + tid];
  __syncthreads();
  float m2 = red[0];
  #pragma unroll
  for (int g = 1; g < 8; g++) m2 = fmaxf(m2, red[g]);

  const int pi = tid >> 3;                   // P row 0..63
  const int pj = (tid & 7) * 8;              // 8 j's per thread
  const float s1v = s1s[pi];
  const float xm = s1v + m2;
  const float mv = fmaxf(xm, 0.2f * xm);     // upper bound on row max (lrelu monotone)
  const unsigned long long* abrow = ab + (size_t)(i0 + pi) * 32;
  float rs = 0.f;

  f32x4 acc[4][2];
  #pragma unroll
  for (int i = 0; i < 4; i++)
    #pragma unroll
    for (int j = 0; j < 2; j++){ acc[i][j][0]=0.f; acc[i][j][1]=0.f; acc[i][j][2]=0.f; acc[i][j][3]=0.f; }

  auto loadB = [&](int j0, bf16x8* dst){
    #pragma unroll
    for (int ot = 0; ot < 2; ot++)
      #pragma unroll
      for (int kk = 0; kk < 2; kk++)
        dst[ot * 2 + kk] = *(const bf16x8*)(WhT + (size_t)(b * 256 + wc + ot * 16 + llo) * 2048 + j0 + kk * 32 + lhi * 8);
  };

  auto stage = [&](int jj, bf16x8* cur, bf16x8* nxt, bool ld){
    // ---- P tile 64x64, each element once; truncation-pack; rs from truncated values ----
    unsigned bits = (unsigned)((abrow[jj >> 6] >> pj) & 0xFFull);
    float4 xa = *(const float4*)&s2s[jj + pj];
    float4 xb = *(const float4*)&s2s[jj + pj + 4];
    float xs[8] = {xa.x, xa.y, xa.z, xa.w, xb.x, xb.y, xb.z, xb.w};
    unsigned pu[8];
    #pragma unroll
    for (int e = 0; e < 8; e++){
      float x = s1v + xs[e];
      float y = fmaxf(x, 0.2f * x) - mv;
      float p = ((bits >> e) & 1u) ? __builtin_amdgcn_exp2f(y) : 0.0f;
      unsigned u = __float_as_uint(p) & 0xFFFF0000u;
      rs += __uint_as_float(u);
      pu[e] = u;
    }
    uint4 q = make_uint4(permpack(pu[1], pu[0]), permpack(pu[3], pu[2]),
                         permpack(pu[5], pu[4]), permpack(pu[7], pu[6]));
    __syncthreads();                        // prev MFMA done reading Ps
    *(uint4*)&Ps[pi * 72 + pj] = q;
    __syncthreads();
    if (ld) loadB(jj + 64, nxt);            // B-frags fly during MFMA
    #pragma unroll
    for (int kk = 0; kk < 2; kk++){
      bf16x8 af[4];
      #pragma unroll
      for (int it = 0; it < 4; it++)
        af[it] = *(const bf16x8*)&Ps[(it * 16 + llo) * 72 + kk * 32 + lhi * 8];
      #pragma unroll
      for (int it = 0; it < 4; it++)
        #pragma unroll
        for (int ot = 0; ot < 2; ot++)
          acc[it][ot] = __builtin_amdgcn_mfma_f32_16x16x32_bf16(af[it], cur[ot * 2 + kk], acc[it][ot], 0, 0, 0);
    }
  };

  bf16x8 b0[4], b1[4];
  loadB(0, b0);
  for (int j0 = 0; j0 < NN; j0 += 128){
    stage(j0,      b0, b1, true);
    stage(j0 + 64, b1, b0, (j0 + 128) < NN);
  }

  // ---- row sums -> 1/l ----
  rs += __shfl_xor(rs, 1);
  rs += __shfl_xor(rs, 2);
  rs += __shfl_xor(rs, 4);
  if ((tid & 7) == 0) lin[pi] = 1.0f / rs;
  __syncthreads();

  // ---- epilogue: scale + store ----
  #pragma unroll
  for (int it = 0; it < 4; it++){
    #pragma unroll
    for (int ot = 0; ot < 2; ot++){
      int col = wc + ot * 16 + llo;
      #pragma unroll
      for (int q = 0; q < 4; q++){
        int row = it * 16 + lhi * 4 + q;
        out[(size_t)(b * NN + i0 + row) * 256 + col] = acc[it][ot][q] * lin[row];
      }
    }
  }
}

extern "C" void kernel_launch(void* const* d_in, const int* in_sizes, int n_in,
                              void* d_out, int out_size, void* d_ws, size_t ws_size,
                              hipStream_t stream) {
  const float* h   = (const float*)d_in[0];
  const float* adj = (const float*)d_in[1];
  const float* W   = (const float*)d_in[2];
  const float* a   = (const float*)d_in[3];
  float* out = (float*)d_out;

  char* ws = (char*)d_ws;
  unsigned short* WhT      = (unsigned short*)(ws);                 // 8,388,608 B
  unsigned short* Wt       = (unsigned short*)(ws + 8388608);       //   131,072 B
  unsigned long long* ab   = (unsigned long long*)(ws + 8519680);   //   524,288 B
  float* s1c               = (float*)(ws + 9043968);                //    65,536 B
  float* s2c               = (float*)(ws + 9109504);                //    65,536 B

  hipLaunchKernelGGL(k_prep,       dim3(2304),   dim3(256), 0, stream, adj, W, ab, Wt);
  hipLaunchKernelGGL(k_fused_gemm, dim3(256),    dim3(512), 0, stream, h, Wt, a, WhT, s1c, s2c);
  hipLaunchKernelGGL(k_attn,       dim3(32, 8),  dim3(512), 0, stream, s1c, s2c, WhT, ab, out);
}